// Round 17
// baseline (153.501 us; speedup 1.0000x reference)
//
#include <hip/hip_runtime.h>
#include <hip/hip_bf16.h>
#include <math.h>

#define S_LEN 4096
#define HID   1280
#define NH    16
#define HD    80
#define HDP   96
#define N3    3840
#define KVB   64

typedef __bf16 bf16_t;
typedef __bf16 bf16x4 __attribute__((ext_vector_type(4)));
typedef __bf16 bf16x8 __attribute__((ext_vector_type(8)));
typedef float  f32x4  __attribute__((ext_vector_type(4)));

__device__ inline void gload_lds16(const bf16_t* g, const bf16_t* lds_base){
  __builtin_amdgcn_global_load_lds((const __attribute__((address_space(1))) void*)g,
                                   (__attribute__((address_space(3))) void*)lds_base,
                                   16, 0, 0);
}

__device__ inline float exp2fast(float x){
#if __has_builtin(__builtin_amdgcn_exp2f)
  return __builtin_amdgcn_exp2f(x);
#else
  return __expf(x * 0.69314718055994531f);
#endif
}

// column permutation: within each q/k head, col 2m <- d=m, col 2m+1 <- d=m+40.
// QK^T is d-order invariant as long as q,k share the order; v unchanged.
__device__ inline int qkv_src_col(int n){
  if (n >= 2 * HID) return n;
  int sec = n / HID;
  int l = n - sec * HID;
  int h = l / 80, d = l - h * 80;
  return sec * HID + h * 80 + (d >> 1) + (d & 1) * 40;
}

// ---------------- prep kernels ----------------

__global__ void k_f2bf(const float* __restrict__ in, bf16_t* __restrict__ out, int n4){
  int i = blockIdx.x * blockDim.x + threadIdx.x;
  int stride = gridDim.x * blockDim.x;
  for (; i < n4; i += stride){
    float4 v = ((const float4*)in)[i];
    bf16x4 o;
    o[0] = (bf16_t)v.x; o[1] = (bf16_t)v.y; o[2] = (bf16_t)v.z; o[3] = (bf16_t)v.w;
    ((bf16x4*)out)[i] = o;
  }
}

// wo: K x N f32 -> N x K bf16 (identity transpose)
__global__ __launch_bounds__(256) void k_transpose_bf(const float* __restrict__ in, bf16_t* __restrict__ out,
                                                      int K, int N){
  __shared__ bf16_t tile[64][65];
  const int tid = threadIdx.x;
  const int n0 = blockIdx.x * 64, k0 = blockIdx.y * 64;
  const int ln = tid & 63, w = tid >> 6;
  #pragma unroll
  for (int p = 0; p < 16; ++p){
    int k = w + p * 4;
    tile[k][ln] = (bf16_t)in[(size_t)(k0 + k) * N + n0 + ln];
  }
  __syncthreads();
  const int lk = tid & 63;
  #pragma unroll
  for (int p = 0; p < 16; ++p){
    int n = w + p * 4;
    out[(size_t)(n0 + n) * K + k0 + lk] = tile[lk][n];
  }
}

// wqkv: HID x N3 f32 -> N3 x HID bf16 with PERMUTED output columns (rope-pair adjacency)
__global__ __launch_bounds__(256) void k_transpose_qkv(const float* __restrict__ in, bf16_t* __restrict__ out){
  __shared__ bf16_t tile[64][65];
  const int tid = threadIdx.x;
  const int n0 = blockIdx.x * 64, k0 = blockIdx.y * 64;
  const int ln = tid & 63, w = tid >> 6;
  const int sc = qkv_src_col(n0 + ln);
  #pragma unroll
  for (int p = 0; p < 16; ++p){
    int k = w + p * 4;
    tile[k][ln] = (bf16_t)in[(size_t)(k0 + k) * N3 + sc];
  }
  __syncthreads();
  const int lk = tid & 63;
  #pragma unroll
  for (int p = 0; p < 16; ++p){
    int n = w + p * 4;
    out[(size_t)(n0 + n) * HID + k0 + lk] = tile[lk][n];
  }
}

// seg bounds + bf16 trig tables + permuted bias. grid 64 x 256.
__global__ void k_seg(const int* __restrict__ cu, const float* __restrict__ rope,
                      const float* __restrict__ bqkv, int* __restrict__ rlo, int* __restrict__ rhi,
                      bf16_t* __restrict__ cs_tab, bf16_t* __restrict__ sn_tab,
                      float* __restrict__ bias_perm){
  const int gtid = blockIdx.x * 256 + threadIdx.x;
  if (gtid < S_LEN){
    int c = 0;
    #pragma unroll
    for (int j = 0; j < 9; ++j) c += (cu[j] <= gtid) ? 1 : 0;
    rlo[gtid] = cu[c - 1];
    rhi[gtid] = cu[c];
  }
  for (int i = gtid; i < S_LEN * 40; i += 64 * 256){
    float sn, cs;
    sincosf(rope[i], &sn, &cs);
    cs_tab[i] = (bf16_t)cs; sn_tab[i] = (bf16_t)sn;
  }
  for (int i = gtid; i < N3; i += 64 * 256)
    bias_perm[i] = bqkv[qkv_src_col(i)];
}

// zero the d=[80,96) pad of q_t/k_t. grid 1024 x 256.
__global__ __launch_bounds__(256) void k_pad(bf16_t* __restrict__ q_t, bf16_t* __restrict__ k_t){
  const int i = blockIdx.x * 256 + threadIdx.x;   // 262144
  const int hs = i >> 2, rem = i & 3;
  bf16_t* p = (rem & 2) ? k_t : q_t;
  size_t off = (size_t)hs * HDP + 80 + (rem & 1) * 8;
  bf16x8 z = (bf16x8)(bf16_t)0.f;
  *(bf16x8*)(p + off) = z;
}

// ---------------- 256x256 8-wave GEMM (QKV), BK=32, tbuf depth-2; fused rope epilogue ----------------
// q,k tiles: rope in-register (pair = lane^1), then per-wave LDS bounce [128][18] ->
// coalesced bf16x8 stores along dperm (8-runs never cross a head: 8|80). bf16 trig in LDS.
// v tiles -> v_T via LDS bounce (r11-proven).
__global__ __launch_bounds__(512, 2) void k_gemm256(const bf16_t* __restrict__ A, const bf16_t* __restrict__ Bt,
                                                    const float* __restrict__ bias_perm,
                                                    bf16_t* __restrict__ q_t, bf16_t* __restrict__ k_t,
                                                    bf16_t* __restrict__ v_T,
                                                    const bf16_t* __restrict__ cs_tab, const bf16_t* __restrict__ sn_tab,
                                                    int M, int N, int K, int nbm){
  __shared__ bf16_t lds[49152];
  const int tid = threadIdx.x;
  const int wv = tid >> 6, lane = tid & 63;
  const int waveM = wv >> 2, waveN = wv & 3;   // 2M x 4N, wave 128x64
  const int g = lane >> 4, l16 = lane & 15;

  const int cpx = gridDim.x >> 3;
  const int bswz = ((int)blockIdx.x & 7) * cpx + ((int)blockIdx.x >> 3);
  const int m0 = (bswz % nbm) * 256, n0 = (bswz / nbm) * 256;

  int srow[4], scol[4];
  #pragma unroll
  for (int i = 0; i < 4; ++i){
    int c = wv + 8 * i;
    int lc = (c < 16) ? c : c - 16;
    int prow = lc * 8 + (lane >> 3);
    int inner = (lane & 7) ^ (lane >> 3);
    srow[i] = prow * 2 + (inner >> 2);
    scol[i] = (inner & 3) * 8;
  }

  const int swzh = (l16 >> 1) & 7;
  const int rcol = ((((l16 & 1) << 2) + g) ^ swzh) * 8;
  int aoff[8], boff[4];
  #pragma unroll
  for (int mi = 0; mi < 8; ++mi)
    aoff[mi] = (waveM * 64 + mi * 8 + (l16 >> 1)) * 64 + rcol;
  #pragma unroll
  for (int ni = 0; ni < 4; ++ni)
    boff[ni] = (waveN * 32 + ni * 8 + (l16 >> 1)) * 64 + rcol;

  f32x4 acc[8][4] = {};
  const int NT = K / 32;   // 40

  auto stage = [&](int t, int bb){
    const int kc = t * 32;
    bf16_t* dst = lds + bb * 16384;
    #pragma unroll
    for (int i = 0; i < 4; ++i){
      int c = wv + 8 * i;
      if (c < 16) gload_lds16(A  + (size_t)(m0 + srow[i]) * K + kc + scol[i], dst + c * 512);
      else        gload_lds16(Bt + (size_t)(n0 + srow[i]) * K + kc + scol[i], dst + 8192 + (c - 16) * 512);
    }
  };

  stage(0, 0);
  stage(1, 1);
  int cur = 0, nxt2 = 2;
  for (int t = 0; t < NT; ++t){
    if (t + 2 < NT){
      stage(t + 2, nxt2);
      asm volatile("s_waitcnt vmcnt(8)" ::: "memory");
    } else if (t + 1 < NT){
      asm volatile("s_waitcnt vmcnt(4)" ::: "memory");
    } else {
      asm volatile("s_waitcnt vmcnt(0)" ::: "memory");
    }
    asm volatile("s_barrier" ::: "memory");

    const bf16_t* Ab = lds + cur * 16384;
    const bf16_t* Bb = Ab + 8192;
    bf16x8 bfv[4], af[8];
    #pragma unroll
    for (int ni = 0; ni < 4; ++ni) bfv[ni] = *(const bf16x8*)(Bb + boff[ni]);
    #pragma unroll
    for (int mi = 0; mi < 8; ++mi) af[mi] = *(const bf16x8*)(Ab + aoff[mi]);
    __builtin_amdgcn_s_setprio(1);
    #pragma unroll
    for (int mi = 0; mi < 8; ++mi)
      #pragma unroll
      for (int ni = 0; ni < 4; ++ni)
        acc[mi][ni] = __builtin_amdgcn_mfma_f32_16x16x32_bf16(af[mi], bfv[ni], acc[mi][ni], 0, 0, 0);
    __builtin_amdgcn_s_setprio(0);
    asm volatile("s_barrier" ::: "memory");
    cur = (cur == 2) ? 0 : cur + 1;
    nxt2 = (nxt2 == 2) ? 0 : nxt2 + 1;
  }

  if (n0 < 2 * HID){
    // ---- rope epilogue with LDS bounce ----
    // layout: per-wave scratch [128][18] bf16 at wv*2304; bf16 trig at 18432 (cs) / 28672 (sn)
    bf16_t* csL = lds + 18432;         // 10240 bf16 (rows m0..m0+256 x 40)
    bf16_t* snL = csL + 10240;
    {
      const bf16x8* csg = (const bf16x8*)(cs_tab + (size_t)m0 * 40);
      const bf16x8* sng = (const bf16x8*)(sn_tab + (size_t)m0 * 40);
      for (int i = tid; i < 1280; i += 512){
        ((bf16x8*)csL)[i] = csg[i];
        ((bf16x8*)snL)[i] = sng[i];
      }
    }
    __syncthreads();
    const bool isq = (n0 < HID);       // block-uniform (HID = 5 n-tiles exactly)
    bf16_t* dst = isq ? q_t : k_t;
    const int nb = isq ? n0 : n0 - HID;
    const float QSCALE = 0.11180339887498949f * 1.4426950408889634f; // 1/sqrt(80)*log2e
    bf16_t* myS = lds + wv * 2304;     // [128 rows][18 cols] bf16
    const int m0w = m0 + waveM * 128;
    #pragma unroll
    for (int ni = 0; ni < 4; ++ni){
      const int col = n0 + waveN * 64 + ni * 16 + l16;
      const int lcq = (isq ? col : col - HID);
      const int dperm = lcq % 80;
      const int dm = dperm >> 1;
      const float sgn = (dperm & 1) ? 1.f : -1.f;
      const float bv = bias_perm[col];
      #pragma unroll
      for (int mi = 0; mi < 8; ++mi){
        const int lrow = mi * 16 + g * 4;            // local row in [0,128)
        #pragma unroll
        for (int r = 0; r < 4; ++r){
          float v = acc[mi][ni][r] + bv;
          float p = __shfl_xor(v, 1);                // rope partner (adjacent permuted col)
          const int lr = waveM * 128 + lrow + r;     // trig row (m0-relative)
          float cs = (float)csL[lr * 40 + dm], snv = (float)snL[lr * 40 + dm];
          float rot = v * cs + sgn * p * snv;
          if (isq) rot *= QSCALE;
          myS[(lrow + r) * 18 + l16] = (bf16_t)rot;  // in-wave DS FIFO: no barrier
        }
      }
      // read back + coalesced store: 256 bf16x8 chunks over 4 iters
      const int lcb = nb + waveN * 64 + ni * 16;     // 8-aligned base col
      #pragma unroll
      for (int it = 0; it < 4; ++it){
        const int id = it * 64 + lane;
        const int row = id >> 1, cc = (id & 1) * 8;
        bf16x8 vv = *(const bf16x8*)(myS + row * 18 + cc);
        const int lc2 = lcb + cc;
        const int hh = lc2 / 80, dp = lc2 % 80;      // 8-run stays in one head (8|80)
        *(bf16x8*)(dst + ((size_t)hh * S_LEN + m0w + row) * HDP + dp) = vv;
      }
    }
  } else {
    // v tile: per-wave LDS transpose bounce -> coalesced v_T stores
    bf16_t* myE = lds + wv * 2112;   // [16 cols][132 rows-pad] bf16
    const int vc0 = n0 - 2 * HID + waveN * 64;
    const int m0w = m0 + waveM * 128;
    #pragma unroll
    for (int ni = 0; ni < 4; ++ni){
      const float bv = bias_perm[n0 + waveN * 64 + ni * 16 + l16];
      #pragma unroll
      for (int mi = 0; mi < 8; ++mi){
        bf16x4 o;
        #pragma unroll
        for (int r = 0; r < 4; ++r) o[r] = (bf16_t)(acc[mi][ni][r] + bv);
        *(bf16x4*)(myE + l16 * 132 + mi * 16 + g * 4) = o;
      }
      #pragma unroll
      for (int p = 0; p < 4; ++p){
        const int dl = p * 4 + g;
        bf16x8 vrow = *(const bf16x8*)(myE + dl * 132 + l16 * 8);
        const int vc = vc0 + ni * 16 + dl;
        const int hh = vc / HD, dd = vc % HD;
        *(bf16x8*)(v_T + ((size_t)hh * HDP + dd) * S_LEN + m0w + l16 * 8) = vrow;
      }
    }
  }
}

// ---------------- 128x64 4-wave GEMM (proj), BK=64, f32 out ----------------
__global__ __launch_bounds__(256, 3) void k_gemm_dp(const bf16_t* __restrict__ A, const bf16_t* __restrict__ Bt,
                                                    const float* __restrict__ bias, float* __restrict__ outp,
                                                    int M, int N, int K, int nbn){
  __shared__ bf16_t lds[24576];
  const int tid = threadIdx.x;
  const int wv = tid >> 6, lane = tid & 63;
  const int wr = wv >> 1, wc = wv & 1;
  const int g = lane >> 4, l16 = lane & 15;

  const int cpx = gridDim.x >> 3;
  const int bswz = ((int)blockIdx.x & 7) * cpx + ((int)blockIdx.x >> 3);
  const int m0 = (bswz / nbn) * 128, n0 = (bswz % nbn) * 64;

  int srow[6];
  const int scol = ((lane & 7) ^ (lane >> 3)) * 8;
  #pragma unroll
  for (int i = 0; i < 6; ++i){
    int c = wv + 4 * i;
    int lc = (c < 16) ? c : c - 16;
    srow[i] = lc * 8 + (lane >> 3);
  }

  const int swz = l16 & 7;
  int aoff[4][2], boff[2][2];
  #pragma unroll
  for (int mi = 0; mi < 4; ++mi)
    #pragma unroll
    for (int kk = 0; kk < 2; ++kk)
      aoff[mi][kk] = (wr * 64 + mi * 16 + l16) * 64 + ((kk * 4 + g) ^ swz) * 8;
  #pragma unroll
  for (int ni = 0; ni < 2; ++ni)
    #pragma unroll
    for (int kk = 0; kk < 2; ++kk)
      boff[ni][kk] = (wc * 32 + ni * 16 + l16) * 64 + ((kk * 4 + g) ^ swz) * 8;

  f32x4 acc[4][2] = {};
  const int NT = K / 64;

  auto stage = [&](int t, int bb){
    const int kc = t * 64;
    #pragma unroll
    for (int i = 0; i < 6; ++i){
      int c = wv + 4 * i;
      if (c < 16) gload_lds16(A  + (size_t)(m0 + srow[i]) * K + kc + scol, lds + bb * 12288 + c * 512);
      else        gload_lds16(Bt + (size_t)(n0 + srow[i]) * K + kc + scol, lds + bb * 12288 + 8192 + (c - 16) * 512);
    }
  };

  stage(0, 0);
  int cur = 0;
  for (int t = 0; t < NT; ++t){
    if (t + 1 < NT){
      stage(t + 1, cur ^ 1);
      asm volatile("s_waitcnt vmcnt(6)" ::: "memory");
    } else {
      asm volatile("s_waitcnt vmcnt(0)" ::: "memory");
    }
    asm volatile("s_barrier" ::: "memory");

    const bf16_t* Ab = lds + cur * 12288;
    const bf16_t* Bb = Ab + 8192;
    #pragma unroll
    for (int kk = 0; kk < 2; ++kk){
      bf16x8 af[4], bfv[2];
      #pragma unroll
      for (int ni = 0; ni < 2; ++ni) bfv[ni] = *(const bf16x8*)(Bb + boff[ni][kk]);
      #pragma unroll
      for (int mi = 0; mi < 4; ++mi) af[mi] = *(const bf16x8*)(Ab + aoff[mi][kk]);
      __builtin_amdgcn_s_setprio(1);
      #pragma unroll
      for (int mi = 0; mi < 4; ++mi)
        #pragma unroll
        for (int ni = 0; ni < 2; ++ni)
          acc[mi][ni] = __builtin_amdgcn_mfma_f32_16x16x32_bf16(af[mi], bfv[ni], acc[mi][ni], 0, 0, 0);
      __builtin_amdgcn_s_setprio(0);
    }
    asm volatile("s_barrier" ::: "memory");
    cur ^= 1;
  }

  #pragma unroll
  for (int ni = 0; ni < 2; ++ni){
    const int col = n0 + wc * 32 + ni * 16 + l16;
    const float bv = bias[col];
    #pragma unroll
    for (int mi = 0; mi < 4; ++mi){
      const int row = m0 + wr * 64 + mi * 16 + g * 4;
      #pragma unroll
      for (int r = 0; r < 4; ++r)
        outp[(size_t)(row + r) * N + col] = acc[mi][ni][r] + bv;
    }
  }
}

// ---------------- flash attention: 8 waves share one staged K/V tile (r14-proven) ----------------
__global__ __launch_bounds__(512, 2) void k_attn(const bf16_t* __restrict__ q_t, const bf16_t* __restrict__ k_t,
                                                 const bf16_t* __restrict__ v_T, const int* __restrict__ rlo,
                                                 const int* __restrict__ rhi, bf16_t* __restrict__ attn){
  __shared__ bf16_t sLds[32768];   // 2*11776 dbuf + 8*1152 P (elems)

  const int b = blockIdx.x;
  const int xcd = b & 7, bi = b >> 3;
  const int h  = xcd * 2 + (bi & 1);
  const int qb = bi >> 1;

  const int tid = threadIdx.x;
  const int wave = tid >> 6, lane = tid & 63;
  const int g = lane >> 4, l16 = lane & 15;
  const int q0 = qb * 128 + wave * 16;
  const size_t hq = (size_t)h * S_LEN;
  const bf16_t* vbase = v_T + (size_t)h * HDP * S_LEN;

  bf16_t* pbase = sLds + 23552 + wave * 1152;

  const int nchunk = (wave < 7) ? 3 : 2;
  int soff[3];
  #pragma unroll
  for (int i = 0; i < 3; ++i){
    int c = wave + 8 * i;
    if (c < 13){
      int p = c * 1024 + lane * 16;
      int row = p / 208, slot = (p % 208) >> 4;
      soff[i] = row * 96 + slot * 8;
    } else if (c < 23){
      int cv = c - 13;
      int row = cv * 8 + (lane >> 3);
      int s = (lane & 7) ^ (row & 7);
      soff[i] = row * S_LEN + s * 8;
    } else soff[i] = 0;
  }

  bf16x8 qf[3];
  #pragma unroll
  for (int c = 0; c < 3; ++c)
    qf[c] = *(const bf16x8*)(q_t + (hq + q0 + l16) * HDP + c * 32 + g * 8);

  const int my_lo = rlo[q0 + l16], my_hi = rhi[q0 + l16];
  const int w_lo = rlo[q0], w_hi = rhi[q0 + 15];
  const int flo = rlo[q0 + 15], fhi = rhi[q0];
  const int lo_blk = rlo[qb * 128] & ~(KVB - 1);
  const int hi_blk = rhi[qb * 128 + 127];
  const int NT = (hi_blk - lo_blk + KVB - 1) / KVB;

  float m_run = -30.f, l_run = 0.f;
  f32x4 acc[5] = {};

  auto stage = [&](int t, int bb){
    const int kv0 = lo_blk + t * KVB;
    const bf16_t* kb = k_t + (hq + kv0) * HDP;
    const bf16_t* vb = vbase + kv0;
    bf16_t* dst = sLds + bb * 11776;
    #pragma unroll
    for (int i = 0; i < 3; ++i){
      int c = wave + 8 * i;
      if (i < nchunk){
        if (c < 13) gload_lds16(kb + soff[i], dst + c * 512);
        else        gload_lds16(vb + soff[i], dst + 6656 + (c - 13) * 512);
      }
    }
  };

  stage(0, 0);
  int cur = 0;
  for (int t = 0; t < NT; ++t){
    if (t + 1 < NT){
      stage(t + 1, cur ^ 1);
      if (wave < 7) asm volatile("s_waitcnt vmcnt(3)" ::: "memory");
      else          asm volatile("s_waitcnt vmcnt(2)" ::: "memory");
    } else {
      asm volatile("s_waitcnt vmcnt(0)" ::: "memory");
    }
    asm volatile("s_barrier" ::: "memory");

    const int kv0 = lo_blk + t * KVB;
    const bf16_t* kbuf = sLds + cur * 11776;
    const bf16_t* vbuf = kbuf + 6656;

    if (!(kv0 + KVB <= w_lo || kv0 >= w_hi)){
      f32x4 sc[4];
      #pragma unroll
      for (int j = 0; j < 4; ++j){
        f32x4 tacc = {0.f, 0.f, 0.f, 0.f};
        #pragma unroll
        for (int c = 0; c < 3; ++c){
          bf16x8 kf = *(const bf16x8*)(kbuf + (j * 16 + l16) * 104 + (4 * c + g) * 8);
          tacc = __builtin_amdgcn_mfma_f32_16x16x32_bf16(kf, qf[c], tacc, 0, 0, 0);
        }
        sc[j] = tacc;
      }

      if (!(kv0 >= flo && kv0 + KVB <= fhi)){
        #pragma unroll
        for (int j = 0; j < 4; ++j)
          #pragma unroll
          for (int r = 0; r < 4; ++r){
            int kvi = kv0 + j * 16 + g * 4 + r;
            if (kvi < my_lo || kvi >= my_hi) sc[j][r] = -1e30f;
          }
      }

      float mx = fmaxf(fmaxf(sc[0][0], sc[0][1]), fmaxf(sc[0][2], sc[0][3]));
      #pragma unroll
      for (int j = 1; j < 4; ++j)
        mx = fmaxf(mx, fmaxf(fmaxf(sc[j][0], sc[j][1]), fmaxf(sc[j][2], sc[j][3])));

      if (!__all(mx <= m_run + 8.0f)){
        float m1 = fmaxf(mx, __shfl_xor(mx, 16));
        float m2 = fmaxf(m1, __shfl_xor(m1, 32));
        float mn = fmaxf(m_run, m2);
        float fr = exp2fast(m_run - mn);
        m_run = mn;
        l_run *= fr;
        #pragma unroll
        for (int ni = 0; ni < 5; ++ni)
          #pragma unroll
          for (int r = 0; r < 4; ++r)
            acc[ni][r] *= fr;
      }

      #pragma unroll
      for (int j = 0; j < 4; ++j){
        bf16x4 pv;
        #pragma unroll
        for (int r = 0; r < 4; ++r){
          float pe = exp2fast(sc[j][r] - m_run);
          l_run += pe;
          pv[r] = (bf16_t)pe;
        }
        *(bf16x4*)(pbase + l16 * 72 + j * 16 + g * 4) = pv;
      }

      bf16x8 pa[2];
      #pragma unroll
      for (int ks = 0; ks < 2; ++ks)
        pa[ks] = *(const bf16x8*)(pbase + l16 * 72 + ks * 32 + g * 8);
      #pragma unroll
      for (int ni = 0; ni < 5; ++ni){
        const int d = ni * 16 + l16;
        #pragma unroll
        for (int ks = 0; ks < 2; ++ks){
          bf16x8 vf = *(const bf16x8*)(vbuf + d * 64 + (((ks * 4 + g) ^ (d & 7)) * 8));
          acc[ni] = __builtin_amdgcn_mfma_f32_16x16x32_bf16(vf, pa[ks], acc[ni], 0, 0, 0);
        }
      }
    }
    asm volatile("s_barrier" ::: "memory");
    cur ^= 1;
  }

  l_run += __shfl_xor(l_run, 16);
  l_run += __shfl_xor(l_run, 32);
  const float inv = 1.f / l_run;
  #pragma unroll
  for (int ni = 0; ni < 5; ++ni)
    #pragma unroll
    for (int r = 0; r < 4; ++r)
      attn[(size_t)(q0 + l16) * HID + h * HD + ni * 16 + g * 4 + r] = (bf16_t)(acc[ni][r] * inv);
}

// ---------------- launch ----------------

extern "C" void kernel_launch(void* const* d_in, const int* in_sizes, int n_in,
                              void* d_out, int out_size, void* d_ws, size_t ws_size,
                              hipStream_t stream){
  const float* x    = (const float*)d_in[0];
  const float* rope = (const float*)d_in[1];
  const int*   cu   = (const int*)  d_in[2];
  const float* wqkv = (const float*)d_in[3];
  const float* bqkv = (const float*)d_in[4];
  const float* wo   = (const float*)d_in[5];
  const float* bo   = (const float*)d_in[6];
  float* out = (float*)d_out;

  char* ws = (char*)d_ws;
  size_t off = 0;
  auto alloc = [&](size_t bytes) -> void* {
    void* p = ws + off;
    off += (bytes + 255) & ~(size_t)255;
    return p;
  };
  bf16_t* x_bf   = (bf16_t*)alloc((size_t)S_LEN * HID * 2);
  bf16_t* w_t    = (bf16_t*)alloc((size_t)N3 * HID * 2);
  bf16_t* wo_t   = (bf16_t*)alloc((size_t)HID * HID * 2);
  bf16_t* q_t    = (bf16_t*)alloc((size_t)NH * S_LEN * HDP * 2);
  bf16_t* k_t    = (bf16_t*)alloc((size_t)NH * S_LEN * HDP * 2);
  bf16_t* v_T    = (bf16_t*)alloc((size_t)NH * HDP * S_LEN * 2);
  bf16_t* cs_tab = (bf16_t*)alloc((size_t)S_LEN * 40 * 2);
  bf16_t* sn_tab = (bf16_t*)alloc((size_t)S_LEN * 40 * 2);
  float* bias_p  = (float*)alloc((size_t)N3 * 4);
  int* rlo = (int*)alloc(S_LEN * 4);
  int* rhi = (int*)alloc(S_LEN * 4);
  bf16_t* attn_bf = x_bf;  // alias: x_bf dead after QKV GEMM

  k_f2bf<<<1024, 256, 0, stream>>>(x, x_bf, S_LEN * HID / 4);
  k_transpose_qkv<<<dim3(N3 / 64, HID / 64), 256, 0, stream>>>(wqkv, w_t);
  k_transpose_bf<<<dim3(HID / 64, HID / 64), 256, 0, stream>>>(wo, wo_t, HID, HID);
  k_seg<<<64, 256, 0, stream>>>(cu, rope, bqkv, rlo, rhi, cs_tab, sn_tab, bias_p);
  k_pad<<<1024, 256, 0, stream>>>(q_t, k_t);

  // QKV: 256x256 tiles, BK=32, tbuf -> grid 240; fused rope epilogue -> q_t/k_t/v_T
  k_gemm256<<<(S_LEN / 256) * (N3 / 256), 512, 0, stream>>>(x_bf, w_t, bias_p, q_t, k_t, v_T,
                                                            cs_tab, sn_tab, S_LEN, N3, HID, S_LEN / 256);

  k_attn<<<512, 512, 0, stream>>>(q_t, k_t, v_T, rlo, rhi, attn_bf);

  // proj: grid 32*20 = 640, BK=64
  k_gemm_dp<<<(S_LEN / 128) * (HID / 64), 256, 0, stream>>>(attn_bf, wo_t, bo, out, S_LEN, HID, HID, HID / 64);
}

// Round 18
// 139.590 us; speedup vs baseline: 1.0997x; 1.0997x over previous
//
#include <hip/hip_runtime.h>
#include <hip/hip_bf16.h>
#include <math.h>

#define S_LEN 4096
#define HID   1280
#define NH    16
#define HD    80
#define HDP   96
#define N3    3840
#define KVB   64

typedef __bf16 bf16_t;
typedef __bf16 bf16x4 __attribute__((ext_vector_type(4)));
typedef __bf16 bf16x8 __attribute__((ext_vector_type(8)));
typedef float  f32x4  __attribute__((ext_vector_type(4)));

__device__ inline void gload_lds16(const bf16_t* g, const bf16_t* lds_base){
  __builtin_amdgcn_global_load_lds((const __attribute__((address_space(1))) void*)g,
                                   (__attribute__((address_space(3))) void*)lds_base,
                                   16, 0, 0);
}

__device__ inline float exp2fast(float x){
#if __has_builtin(__builtin_amdgcn_exp2f)
  return __builtin_amdgcn_exp2f(x);
#else
  return __expf(x * 0.69314718055994531f);
#endif
}

// ---------------- merged prep: wqkv-T tiles | wo-T tiles | f2bf | seg ----------------
// blocks [0,1200): wqkv transpose (60x20 tiles of 64x64)
// blocks [1200,1600): wo transpose (20x20 tiles)
// blocks [1600,2880): x f32->bf16 (4 float4/thread, coalesced)
// blocks [2880,2896): segment bounds
__global__ __launch_bounds__(256) void k_prep(const float* __restrict__ x, const float* __restrict__ wqkv,
                                              const float* __restrict__ wo, const int* __restrict__ cu,
                                              bf16_t* __restrict__ x_bf, bf16_t* __restrict__ w_t,
                                              bf16_t* __restrict__ wo_t, int* __restrict__ rlo,
                                              int* __restrict__ rhi){
  __shared__ bf16_t tile[64][65];
  const int b = blockIdx.x;
  const int tid = threadIdx.x;
  if (b < 1600){
    const bool isqkv = (b < 1200);
    const int idx = isqkv ? b : b - 1200;
    const int nbx = isqkv ? 60 : 20;
    const int NN  = isqkv ? N3 : HID;
    const float* in = isqkv ? wqkv : wo;
    bf16_t* out = isqkv ? w_t : wo_t;
    const int n0 = (idx % nbx) * 64, k0 = (idx / nbx) * 64;
    const int ln = tid & 63, w = tid >> 6;
    #pragma unroll
    for (int p = 0; p < 16; ++p){
      int k = w + p * 4;
      tile[k][ln] = (bf16_t)in[(size_t)(k0 + k) * NN + n0 + ln];
    }
    __syncthreads();
    const int lk = tid & 63;
    #pragma unroll
    for (int p = 0; p < 16; ++p){
      int n = w + p * 4;
      out[(size_t)(n0 + n) * HID + k0 + lk] = tile[lk][n];
    }
  } else if (b < 2880){
    const int i = (b - 1600) * 256 + tid;        // 0 .. 327679
    const float4* in4 = (const float4*)x;
    #pragma unroll
    for (int p = 0; p < 4; ++p){
      int j = i + p * 327680;                    // coalesced sweeps; 4*327680 = 1310720 float4
      float4 v = in4[j];
      bf16x4 o;
      o[0] = (bf16_t)v.x; o[1] = (bf16_t)v.y; o[2] = (bf16_t)v.z; o[3] = (bf16_t)v.w;
      ((bf16x4*)x_bf)[j] = o;
    }
  } else {
    const int s = (b - 2880) * 256 + tid;
    if (s < S_LEN){
      int c = 0;
      #pragma unroll
      for (int j = 0; j < 9; ++j) c += (cu[j] <= s) ? 1 : 0;
      rlo[s] = cu[c - 1];
      rhi[s] = cu[c];
    }
  }
}

// ---------------- 256x256 8-wave GEMM (QKV), BK=32, triple-buffer depth-2, bf16 out ----------------
// q,k cols -> qkv row-major; v cols -> v_T via per-wave LDS transpose bounce. (r14-proven)
__global__ __launch_bounds__(512, 2) void k_gemm256(const bf16_t* __restrict__ A, const bf16_t* __restrict__ Bt,
                                                    const float* __restrict__ bias, bf16_t* __restrict__ outp,
                                                    bf16_t* __restrict__ v_T,
                                                    int M, int N, int K, int nbm){
  __shared__ bf16_t lds[49152];
  const int tid = threadIdx.x;
  const int wv = tid >> 6, lane = tid & 63;
  const int waveM = wv >> 2, waveN = wv & 3;   // 2M x 4N, wave 128x64
  const int g = lane >> 4, l16 = lane & 15;

  const int cpx = gridDim.x >> 3;
  const int bswz = ((int)blockIdx.x & 7) * cpx + ((int)blockIdx.x >> 3);
  const int m0 = (bswz % nbm) * 256, n0 = (bswz / nbm) * 256;   // n-major: B L2-resident

  int srow[4], scol[4];
  #pragma unroll
  for (int i = 0; i < 4; ++i){
    int c = wv + 8 * i;
    int lc = (c < 16) ? c : c - 16;
    int prow = lc * 8 + (lane >> 3);
    int inner = (lane & 7) ^ (lane >> 3);
    srow[i] = prow * 2 + (inner >> 2);
    scol[i] = (inner & 3) * 8;
  }

  const int swzh = (l16 >> 1) & 7;
  const int rcol = ((((l16 & 1) << 2) + g) ^ swzh) * 8;
  int aoff[8], boff[4];
  #pragma unroll
  for (int mi = 0; mi < 8; ++mi)
    aoff[mi] = (waveM * 64 + mi * 8 + (l16 >> 1)) * 64 + rcol;
  #pragma unroll
  for (int ni = 0; ni < 4; ++ni)
    boff[ni] = (waveN * 32 + ni * 8 + (l16 >> 1)) * 64 + rcol;

  f32x4 acc[8][4] = {};
  const int NT = K / 32;   // 40

  auto stage = [&](int t, int bb){
    const int kc = t * 32;
    bf16_t* dst = lds + bb * 16384;
    #pragma unroll
    for (int i = 0; i < 4; ++i){
      int c = wv + 8 * i;
      if (c < 16) gload_lds16(A  + (size_t)(m0 + srow[i]) * K + kc + scol[i], dst + c * 512);
      else        gload_lds16(Bt + (size_t)(n0 + srow[i]) * K + kc + scol[i], dst + 8192 + (c - 16) * 512);
    }
  };

  stage(0, 0);
  stage(1, 1);
  int cur = 0, nxt2 = 2;
  for (int t = 0; t < NT; ++t){
    if (t + 2 < NT){
      stage(t + 2, nxt2);
      asm volatile("s_waitcnt vmcnt(8)" ::: "memory");
    } else if (t + 1 < NT){
      asm volatile("s_waitcnt vmcnt(4)" ::: "memory");
    } else {
      asm volatile("s_waitcnt vmcnt(0)" ::: "memory");
    }
    asm volatile("s_barrier" ::: "memory");

    const bf16_t* Ab = lds + cur * 16384;
    const bf16_t* Bb = Ab + 8192;
    bf16x8 bfv[4], af[8];
    #pragma unroll
    for (int ni = 0; ni < 4; ++ni) bfv[ni] = *(const bf16x8*)(Bb + boff[ni]);
    #pragma unroll
    for (int mi = 0; mi < 8; ++mi) af[mi] = *(const bf16x8*)(Ab + aoff[mi]);
    __builtin_amdgcn_s_setprio(1);
    #pragma unroll
    for (int mi = 0; mi < 8; ++mi)
      #pragma unroll
      for (int ni = 0; ni < 4; ++ni)
        acc[mi][ni] = __builtin_amdgcn_mfma_f32_16x16x32_bf16(af[mi], bfv[ni], acc[mi][ni], 0, 0, 0);
    __builtin_amdgcn_s_setprio(0);
    asm volatile("s_barrier" ::: "memory");
    cur = (cur == 2) ? 0 : cur + 1;
    nxt2 = (nxt2 == 2) ? 0 : nxt2 + 1;
  }

  if (n0 < 2 * HID){
    #pragma unroll
    for (int ni = 0; ni < 4; ++ni){
      const int col = n0 + waveN * 64 + ni * 16 + l16;
      const float bv = bias[col];
      #pragma unroll
      for (int mi = 0; mi < 8; ++mi){
        const int row = m0 + waveM * 128 + mi * 16 + g * 4;
        #pragma unroll
        for (int r = 0; r < 4; ++r)
          outp[(size_t)(row + r) * N + col] = (bf16_t)(acc[mi][ni][r] + bv);
      }
    }
  } else {
    bf16_t* myE = lds + wv * 2112;   // [16 cols][132 rows-pad] bf16
    const int vc0 = n0 - 2 * HID + waveN * 64;
    const int m0w = m0 + waveM * 128;
    #pragma unroll
    for (int ni = 0; ni < 4; ++ni){
      const float bv = bias[n0 + waveN * 64 + ni * 16 + l16];
      #pragma unroll
      for (int mi = 0; mi < 8; ++mi){
        bf16x4 o;
        #pragma unroll
        for (int r = 0; r < 4; ++r) o[r] = (bf16_t)(acc[mi][ni][r] + bv);
        *(bf16x4*)(myE + l16 * 132 + mi * 16 + g * 4) = o;
      }
      #pragma unroll
      for (int p = 0; p < 4; ++p){
        const int dl = p * 4 + g;
        bf16x8 vrow = *(const bf16x8*)(myE + dl * 132 + l16 * 8);
        const int vc = vc0 + ni * 16 + dl;
        const int hh = vc / HD, dd = vc % HD;
        *(bf16x8*)(v_T + ((size_t)hh * HDP + dd) * S_LEN + m0w + l16 * 8) = vrow;
      }
    }
  }
}

// ---------------- 128x64 4-wave GEMM (proj), BK=64, f32 out ----------------
__global__ __launch_bounds__(256, 3) void k_gemm_dp(const bf16_t* __restrict__ A, const bf16_t* __restrict__ Bt,
                                                    const float* __restrict__ bias, float* __restrict__ outp,
                                                    int M, int N, int K, int nbn){
  __shared__ bf16_t lds[24576];
  const int tid = threadIdx.x;
  const int wv = tid >> 6, lane = tid & 63;
  const int wr = wv >> 1, wc = wv & 1;
  const int g = lane >> 4, l16 = lane & 15;

  const int cpx = gridDim.x >> 3;
  const int bswz = ((int)blockIdx.x & 7) * cpx + ((int)blockIdx.x >> 3);
  const int m0 = (bswz / nbn) * 128, n0 = (bswz % nbn) * 64;

  int srow[6];
  const int scol = ((lane & 7) ^ (lane >> 3)) * 8;
  #pragma unroll
  for (int i = 0; i < 6; ++i){
    int c = wv + 4 * i;
    int lc = (c < 16) ? c : c - 16;
    srow[i] = lc * 8 + (lane >> 3);
  }

  const int swz = l16 & 7;
  int aoff[4][2], boff[2][2];
  #pragma unroll
  for (int mi = 0; mi < 4; ++mi)
    #pragma unroll
    for (int kk = 0; kk < 2; ++kk)
      aoff[mi][kk] = (wr * 64 + mi * 16 + l16) * 64 + ((kk * 4 + g) ^ swz) * 8;
  #pragma unroll
  for (int ni = 0; ni < 2; ++ni)
    #pragma unroll
    for (int kk = 0; kk < 2; ++kk)
      boff[ni][kk] = (wc * 32 + ni * 16 + l16) * 64 + ((kk * 4 + g) ^ swz) * 8;

  f32x4 acc[4][2] = {};
  const int NT = K / 64;

  auto stage = [&](int t, int bb){
    const int kc = t * 64;
    #pragma unroll
    for (int i = 0; i < 6; ++i){
      int c = wv + 4 * i;
      if (c < 16) gload_lds16(A  + (size_t)(m0 + srow[i]) * K + kc + scol, lds + bb * 12288 + c * 512);
      else        gload_lds16(Bt + (size_t)(n0 + srow[i]) * K + kc + scol, lds + bb * 12288 + 8192 + (c - 16) * 512);
    }
  };

  stage(0, 0);
  int cur = 0;
  for (int t = 0; t < NT; ++t){
    if (t + 1 < NT){
      stage(t + 1, cur ^ 1);
      asm volatile("s_waitcnt vmcnt(6)" ::: "memory");
    } else {
      asm volatile("s_waitcnt vmcnt(0)" ::: "memory");
    }
    asm volatile("s_barrier" ::: "memory");

    const bf16_t* Ab = lds + cur * 12288;
    const bf16_t* Bb = Ab + 8192;
    #pragma unroll
    for (int kk = 0; kk < 2; ++kk){
      bf16x8 af[4], bfv[2];
      #pragma unroll
      for (int ni = 0; ni < 2; ++ni) bfv[ni] = *(const bf16x8*)(Bb + boff[ni][kk]);
      #pragma unroll
      for (int mi = 0; mi < 4; ++mi) af[mi] = *(const bf16x8*)(Ab + aoff[mi][kk]);
      __builtin_amdgcn_s_setprio(1);
      #pragma unroll
      for (int mi = 0; mi < 4; ++mi)
        #pragma unroll
        for (int ni = 0; ni < 2; ++ni)
          acc[mi][ni] = __builtin_amdgcn_mfma_f32_16x16x32_bf16(af[mi], bfv[ni], acc[mi][ni], 0, 0, 0);
      __builtin_amdgcn_s_setprio(0);
    }
    asm volatile("s_barrier" ::: "memory");
    cur ^= 1;
  }

  #pragma unroll
  for (int ni = 0; ni < 2; ++ni){
    const int col = n0 + wc * 32 + ni * 16 + l16;
    const float bv = bias[col];
    #pragma unroll
    for (int mi = 0; mi < 4; ++mi){
      const int row = m0 + wr * 64 + mi * 16 + g * 4;
      #pragma unroll
      for (int r = 0; r < 4; ++r)
        outp[(size_t)(row + r) * N + col] = acc[mi][ni][r] + bv;
    }
  }
}

// ---------------- RoPE (q pre-scaled by log2e/sqrt(HD) for exp2-domain softmax) ----------------
__global__ void k_rope(const bf16_t* __restrict__ qkv, const float* __restrict__ rope,
                       bf16_t* __restrict__ q_t, bf16_t* __restrict__ k_t){
  const int s = blockIdx.x;
  const int tid = threadIdx.x;
  __shared__ float cs_s[40], sn_s[40];
  if (tid < 40){
    float sn, cs;
    sincosf(rope[s * 40 + tid], &sn, &cs);
    cs_s[tid] = cs; sn_s[tid] = sn;
  }
  __syncthreads();
  const size_t base = (size_t)s * N3;
  const float SCALE = 0.11180339887498949f * 1.4426950408889634f; // 1/sqrt(80) * log2(e)
  for (int t = tid; t < NH * 40; t += 256){
    const int h = t / 40, dm = t % 40;
    const float cs = cs_s[dm], sn = sn_s[dm];
    const int i = h * HD + dm;
    float q1 = (float)qkv[base + i];
    float q2 = (float)qkv[base + i + 40];
    float k1 = (float)qkv[base + HID + i];
    float k2 = (float)qkv[base + HID + i + 40];
    size_t o = ((size_t)h * S_LEN + s) * HDP + dm;
    q_t[o]      = (bf16_t)((q1 * cs - q2 * sn) * SCALE);
    q_t[o + 40] = (bf16_t)((q2 * cs + q1 * sn) * SCALE);
    k_t[o]      = (bf16_t)(k1 * cs - k2 * sn);
    k_t[o + 40] = (bf16_t)(k2 * cs + k1 * sn);
  }
  for (int t = tid; t < NH * 16; t += 256){
    const int h = t >> 4, d = HD + (t & 15);
    size_t o = ((size_t)h * S_LEN + s) * HDP + d;
    q_t[o] = (bf16_t)0.f;
    k_t[o] = (bf16_t)0.f;
  }
}

// ---------------- flash attention: 8 waves share one staged K/V tile (r14-proven) ----------------
__global__ __launch_bounds__(512, 2) void k_attn(const bf16_t* __restrict__ q_t, const bf16_t* __restrict__ k_t,
                                                 const bf16_t* __restrict__ v_T, const int* __restrict__ rlo,
                                                 const int* __restrict__ rhi, bf16_t* __restrict__ attn){
  __shared__ bf16_t sLds[32768];   // 2*11776 dbuf + 8*1152 P (elems)

  const int b = blockIdx.x;
  const int xcd = b & 7, bi = b >> 3;
  const int h  = xcd * 2 + (bi & 1);
  const int qb = bi >> 1;

  const int tid = threadIdx.x;
  const int wave = tid >> 6, lane = tid & 63;
  const int g = lane >> 4, l16 = lane & 15;
  const int q0 = qb * 128 + wave * 16;
  const size_t hq = (size_t)h * S_LEN;
  const bf16_t* vbase = v_T + (size_t)h * HDP * S_LEN;

  bf16_t* pbase = sLds + 23552 + wave * 1152;

  const int nchunk = (wave < 7) ? 3 : 2;
  int soff[3];
  #pragma unroll
  for (int i = 0; i < 3; ++i){
    int c = wave + 8 * i;
    if (c < 13){
      int p = c * 1024 + lane * 16;
      int row = p / 208, slot = (p % 208) >> 4;
      soff[i] = row * 96 + slot * 8;
    } else if (c < 23){
      int cv = c - 13;
      int row = cv * 8 + (lane >> 3);
      int s = (lane & 7) ^ (row & 7);
      soff[i] = row * S_LEN + s * 8;
    } else soff[i] = 0;
  }

  bf16x8 qf[3];
  #pragma unroll
  for (int c = 0; c < 3; ++c)
    qf[c] = *(const bf16x8*)(q_t + (hq + q0 + l16) * HDP + c * 32 + g * 8);

  const int my_lo = rlo[q0 + l16], my_hi = rhi[q0 + l16];
  const int w_lo = rlo[q0], w_hi = rhi[q0 + 15];
  const int flo = rlo[q0 + 15], fhi = rhi[q0];
  const int lo_blk = rlo[qb * 128] & ~(KVB - 1);
  const int hi_blk = rhi[qb * 128 + 127];
  const int NT = (hi_blk - lo_blk + KVB - 1) / KVB;

  float m_run = -30.f, l_run = 0.f;
  f32x4 acc[5] = {};

  auto stage = [&](int t, int bb){
    const int kv0 = lo_blk + t * KVB;
    const bf16_t* kb = k_t + (hq + kv0) * HDP;
    const bf16_t* vb = vbase + kv0;
    bf16_t* dst = sLds + bb * 11776;
    #pragma unroll
    for (int i = 0; i < 3; ++i){
      int c = wave + 8 * i;
      if (i < nchunk){
        if (c < 13) gload_lds16(kb + soff[i], dst + c * 512);
        else        gload_lds16(vb + soff[i], dst + 6656 + (c - 13) * 512);
      }
    }
  };

  stage(0, 0);
  int cur = 0;
  for (int t = 0; t < NT; ++t){
    if (t + 1 < NT){
      stage(t + 1, cur ^ 1);
      if (wave < 7) asm volatile("s_waitcnt vmcnt(3)" ::: "memory");
      else          asm volatile("s_waitcnt vmcnt(2)" ::: "memory");
    } else {
      asm volatile("s_waitcnt vmcnt(0)" ::: "memory");
    }
    asm volatile("s_barrier" ::: "memory");

    const int kv0 = lo_blk + t * KVB;
    const bf16_t* kbuf = sLds + cur * 11776;
    const bf16_t* vbuf = kbuf + 6656;

    if (!(kv0 + KVB <= w_lo || kv0 >= w_hi)){
      f32x4 sc[4];
      #pragma unroll
      for (int j = 0; j < 4; ++j){
        f32x4 tacc = {0.f, 0.f, 0.f, 0.f};
        #pragma unroll
        for (int c = 0; c < 3; ++c){
          bf16x8 kf = *(const bf16x8*)(kbuf + (j * 16 + l16) * 104 + (4 * c + g) * 8);
          tacc = __builtin_amdgcn_mfma_f32_16x16x32_bf16(kf, qf[c], tacc, 0, 0, 0);
        }
        sc[j] = tacc;
      }

      if (!(kv0 >= flo && kv0 + KVB <= fhi)){
        #pragma unroll
        for (int j = 0; j < 4; ++j)
          #pragma unroll
          for (int r = 0; r < 4; ++r){
            int kvi = kv0 + j * 16 + g * 4 + r;
            if (kvi < my_lo || kvi >= my_hi) sc[j][r] = -1e30f;
          }
      }

      float mx = fmaxf(fmaxf(sc[0][0], sc[0][1]), fmaxf(sc[0][2], sc[0][3]));
      #pragma unroll
      for (int j = 1; j < 4; ++j)
        mx = fmaxf(mx, fmaxf(fmaxf(sc[j][0], sc[j][1]), fmaxf(sc[j][2], sc[j][3])));

      if (!__all(mx <= m_run + 8.0f)){
        float m1 = fmaxf(mx, __shfl_xor(mx, 16));
        float m2 = fmaxf(m1, __shfl_xor(m1, 32));
        float mn = fmaxf(m_run, m2);
        float fr = exp2fast(m_run - mn);
        m_run = mn;
        l_run *= fr;
        #pragma unroll
        for (int ni = 0; ni < 5; ++ni)
          #pragma unroll
          for (int r = 0; r < 4; ++r)
            acc[ni][r] *= fr;
      }

      #pragma unroll
      for (int j = 0; j < 4; ++j){
        bf16x4 pv;
        #pragma unroll
        for (int r = 0; r < 4; ++r){
          float pe = exp2fast(sc[j][r] - m_run);
          l_run += pe;
          pv[r] = (bf16_t)pe;
        }
        *(bf16x4*)(pbase + l16 * 72 + j * 16 + g * 4) = pv;
      }

      bf16x8 pa[2];
      #pragma unroll
      for (int ks = 0; ks < 2; ++ks)
        pa[ks] = *(const bf16x8*)(pbase + l16 * 72 + ks * 32 + g * 8);
      #pragma unroll
      for (int ni = 0; ni < 5; ++ni){
        const int d = ni * 16 + l16;
        #pragma unroll
        for (int ks = 0; ks < 2; ++ks){
          bf16x8 vf = *(const bf16x8*)(vbuf + d * 64 + (((ks * 4 + g) ^ (d & 7)) * 8));
          acc[ni] = __builtin_amdgcn_mfma_f32_16x16x32_bf16(vf, pa[ks], acc[ni], 0, 0, 0);
        }
      }
    }
    asm volatile("s_barrier" ::: "memory");
    cur ^= 1;
  }

  l_run += __shfl_xor(l_run, 16);
  l_run += __shfl_xor(l_run, 32);
  const float inv = 1.f / l_run;
  #pragma unroll
  for (int ni = 0; ni < 5; ++ni)
    #pragma unroll
    for (int r = 0; r < 4; ++r)
      attn[(size_t)(q0 + l16) * HID + h * HD + ni * 16 + g * 4 + r] = (bf16_t)(acc[ni][r] * inv);
}

// ---------------- launch ----------------

extern "C" void kernel_launch(void* const* d_in, const int* in_sizes, int n_in,
                              void* d_out, int out_size, void* d_ws, size_t ws_size,
                              hipStream_t stream){
  const float* x    = (const float*)d_in[0];
  const float* rope = (const float*)d_in[1];
  const int*   cu   = (const int*)  d_in[2];
  const float* wqkv = (const float*)d_in[3];
  const float* bqkv = (const float*)d_in[4];
  const float* wo   = (const float*)d_in[5];
  const float* bo   = (const float*)d_in[6];
  float* out = (float*)d_out;

  char* ws = (char*)d_ws;
  size_t off = 0;
  auto alloc = [&](size_t bytes) -> void* {
    void* p = ws + off;
    off += (bytes + 255) & ~(size_t)255;
    return p;
  };
  bf16_t* x_bf   = (bf16_t*)alloc((size_t)S_LEN * HID * 2);
  bf16_t* w_t    = (bf16_t*)alloc((size_t)N3 * HID * 2);
  bf16_t* wo_t   = (bf16_t*)alloc((size_t)HID * HID * 2);
  bf16_t* qkv_bf = (bf16_t*)alloc((size_t)S_LEN * N3 * 2);
  bf16_t* q_t    = (bf16_t*)alloc((size_t)NH * S_LEN * HDP * 2);
  bf16_t* k_t    = (bf16_t*)alloc((size_t)NH * S_LEN * HDP * 2);
  bf16_t* v_T    = (bf16_t*)alloc((size_t)NH * HDP * S_LEN * 2);
  int* rlo = (int*)alloc(S_LEN * 4);
  int* rhi = (int*)alloc(S_LEN * 4);
  bf16_t* attn_bf = x_bf;  // alias: x_bf dead after QKV GEMM

  // merged prep: wqkv-T | wo-T | f2bf | seg in ONE launch (2896 blocks)
  k_prep<<<2896, 256, 0, stream>>>(x, wqkv, wo, cu, x_bf, w_t, wo_t, rlo, rhi);

  // QKV: 256x256 tiles, BK=32, triple-buffer -> grid 16*15 = 240 (240%8==0)
  k_gemm256<<<(S_LEN / 256) * (N3 / 256), 512, 0, stream>>>(x_bf, w_t, bqkv, qkv_bf, v_T, S_LEN, N3, HID, S_LEN / 256);

  k_rope<<<S_LEN, 256, 0, stream>>>(qkv_bf, rope, q_t, k_t);

  k_attn<<<512, 512, 0, stream>>>(q_t, k_t, v_T, rlo, rhi, attn_bf);

  // proj: grid 32*20 = 640 (640%8==0), BK=64
  k_gemm_dp<<<(S_LEN / 128) * (HID / 64), 256, 0, stream>>>(attn_bf, wo_t, bo, out, S_LEN, HID, HID, HID / 64);
}